// Round 1
// baseline (354.626 us; speedup 1.0000x reference)
//
#include <hip/hip_runtime.h>
#include <hip/hip_bf16.h>
#include <math.h>

// B=64, L=1024, C=128, K=6, P=6, Dp=8, D=4, Dd=12, ITERS=2
#define EPSQ 1e-9f

typedef float  floatx4 __attribute__((ext_vector_type(4)));
typedef short  short8  __attribute__((ext_vector_type(8)));
typedef unsigned short u16;
typedef unsigned int   u32;

constexpr int TP  = 16;  // positions per block
constexpr int SA  = 40;  // ushort stride, stage-1 A rows (32 data + 8 pad) = 80 B, 16B-aligned
constexpr int SS  = 49;  // dword stride, sU rows (48 data + 1 pad) = 196 B
constexpr int SA2 = 48;  // ushort stride, stage-2 A rows (48 data) = 96 B, 16B-aligned

// LDS plan (single overlaid region, phases separated by barriers):
//   phase 1: sA   = [96][SA] u16 hi + lo           = 15,360 B   (stage-1 X staging)
//   phase 2: sA2  = [96][SA2] u16 hi + lo          = 18,432 B   (stage-2 A fragments, written from regs)
//   phase 3: sU   = [96][SS] f32                   = 18,816 B   (u_hat for routing)
//   + 32 B zero block at 18,816 for quad>=2 chunk-1 A-fragment reads
// total 18,848 B -> 8 blocks/CU (was 35,328 B -> 4 blocks/CU)

// fp32 -> (hi, lo) bf16 pair-packed as u32 (2 elements per call)
__device__ __forceinline__ void cvt_hilo(float a, float b, u32& hi, u32& lo) {
    __hip_bfloat162 h = __float22bfloat162_rn(make_float2(a, b));
    float2 hf = __bfloat1622float2(h);
    __hip_bfloat162 l = __float22bfloat162_rn(make_float2(a - hf.x, b - hf.y));
    __builtin_memcpy(&hi, &h, 4);
    __builtin_memcpy(&lo, &l, 4);
}

__device__ __forceinline__ float g16sum(float x) {
    x += __shfl_xor(x, 1);
    x += __shfl_xor(x, 2);
    x += __shfl_xor(x, 4);
    x += __shfl_xor(x, 8);
    return x;
}

__device__ __forceinline__ float g8sum(float x) {
    x += __shfl_xor(x, 1);
    x += __shfl_xor(x, 2);
    x += __shfl_xor(x, 4);
    return x;
}

// Dynamic routing (ITERS=2), named scalars only (R4 lesson: no local arrays).
__device__ __forceinline__ void route_and_write(float u0, float u1, float u2,
                                                float u3, float u4, float u5,
                                                int d, int q, bool act,
                                                float* __restrict__ out, long pos)
{
    float s = (u0 + u1 + u2 + u3 + u4 + u5) * 0.25f;
    float s2 = g16sum(s * s);
    float v = s * (s2 / (1.0f + s2) / (sqrtf(s2) + EPSQ));

    float ss = 0.f;
#define ROUTE_K(UK)                                        \
    {                                                      \
        float b = g16sum((UK) * v);                        \
        float mm = fmaxf(b, __shfl_xor(b, 16));            \
        mm = fmaxf(mm, __shfl_xor(mm, 32));                \
        float e = __expf(b - mm);                          \
        float es = e + __shfl_xor(e, 16);                  \
        es += __shfl_xor(es, 32);                          \
        ss = fmaf(e / es, (UK), ss);                       \
    }
    ROUTE_K(u0) ROUTE_K(u1) ROUTE_K(u2) ROUTE_K(u3) ROUTE_K(u4) ROUTE_K(u5)
#undef ROUTE_K
    float ss2 = g16sum(ss * ss);
    float vv = ss * (ss2 / (1.0f + ss2) / (sqrtf(ss2) + EPSQ));
    if (act) out[pos * 48 + d * 12 + q] = vv;
}

// ---- prep: convert Wp/W into MFMA-B-fragment-ready bf16 hi/lo layouts in ws. (UNCHANGED)
// wpf: [var2][ct3][kc4][lane64][j8]  = Wp[p=ct*16+(lane&15)][c=kc*32+quad*8+j]
// wf : [var2][k6][ct3][kc2][lane64][j8] = W[k][dq=ct*16+(lane&15)][p=kc*32+quad*8+j], 0 if p>=48
__global__ void prep_kernel(const float* __restrict__ Wp, const float* __restrict__ W,
                            u16* __restrict__ wpf, u16* __restrict__ wf) {
    int gid = blockIdx.x * 256 + threadIdx.x;
    int stride = gridDim.x * 256;
    for (int i = gid; i < 12288; i += stride) {
        int j = i & 7, lane = (i >> 3) & 63, kc = (i >> 9) & 3, vt = i >> 11;
        int var = (vt >= 3) ? 1 : 0;
        int ct = vt - 3 * var;
        int p = ct * 16 + (lane & 15);
        int c = kc * 32 + (lane >> 4) * 8 + j;
        float x = Wp[p * 128 + c];
        __hip_bfloat16 hb = __float2bfloat16(x);
        if (var) { float hf = __bfloat162float(hb); hb = __float2bfloat16(x - hf); }
        u16 u; __builtin_memcpy(&u, &hb, 2);
        wpf[i] = u;
    }
    for (int i = gid; i < 36864; i += stride) {
        int j = i & 7, lane = (i >> 3) & 63, kc = (i >> 9) & 1, q3 = i >> 10;
        int ct = q3 % 3, kk = q3 / 3;       // kk = var*6 + k
        int k = kk % 6, var = kk / 6;
        int dq = ct * 16 + (lane & 15);
        int p = kc * 32 + (lane >> 4) * 8 + j;
        float x = (p < 48) ? W[(k * 48 + dq) * 48 + p] : 0.f;
        __hip_bfloat16 hb = __float2bfloat16(x);
        if (var) { float hf = __bfloat162float(hb); hb = __float2bfloat16(x - hf); }
        u16 u; __builtin_memcpy(&u, &hb, 2);
        wf[i] = u;
    }
}

__global__ __launch_bounds__(256, 8)
void capsule_kernel(
    const float* __restrict__ X,    // [65536][128][6]
    const float* __restrict__ bp,   // [48]
    const u16* __restrict__ wpf,    // prepped Wp fragments
    const u16* __restrict__ wf,     // prepped W fragments
    float* __restrict__ out)        // [65536][48]
{
    __shared__ __align__(16) char raw[18848];
    u16*   sAh  = (u16*)raw;                 // [96][SA]  (phase 1)
    u16*   sAl  = sAh + 96 * SA;
    u16*   sA2h = (u16*)raw;                 // [96][SA2] (phase 2, overlays sA)
    u16*   sA2l = sA2h + 96 * SA2;
    float* sU   = (float*)raw;               // [96][SS]  (phase 3, overlays sA2)
    const u16* zpad = (const u16*)(raw + 18816);  // 32 B of zeros

    const int t    = threadIdx.x;
    const int lane = t & 63;
    const int w    = t >> 6;
    const int m    = lane & 15;
    const int quad = lane >> 4;
    const long pos_base = (long)blockIdx.x * TP;

    if (t < 8) ((u32*)(raw + 18816))[t] = 0u;   // zero block, visible after first barrier

    // ================= stage 1: projection  acc[(pos*6+k)][p] = X·Wp^T (+bp later) ==========
    floatx4 acc_a = {0.f,0.f,0.f,0.f}, acc_b = {0.f,0.f,0.f,0.f}, acc_c = {0.f,0.f,0.f,0.f},
            acc_d = {0.f,0.f,0.f,0.f}, acc_e = {0.f,0.f,0.f,0.f};

#define S1_TILE(ACC, TI)                                                              \
    { int T = w + 4 * (TI);                                                           \
      if (T < 18) {                                                                   \
        int rt = T / 3, ct = T - 3 * rt;                                              \
        short8 ah = *(const short8*)(sAh + (rt * 16 + m) * SA + quad * 8);            \
        short8 al = *(const short8*)(sAl + (rt * 16 + m) * SA + quad * 8);            \
        short8 bh = *(const short8*)(wpf + ((ct * 4 + kc) * 64 + lane) * 8);          \
        short8 bl = *(const short8*)(wpf + (((3 + ct) * 4 + kc) * 64 + lane) * 8);    \
        ACC = __builtin_amdgcn_mfma_f32_16x16x32_bf16(ah, bh, ACC, 0, 0, 0);          \
        ACC = __builtin_amdgcn_mfma_f32_16x16x32_bf16(ah, bl, ACC, 0, 0, 0);          \
        ACC = __builtin_amdgcn_mfma_f32_16x16x32_bf16(al, bh, ACC, 0, 0, 0);          \
      } }

    #pragma unroll
    for (int kc = 0; kc < 4; ++kc) {
        if (kc > 0) __syncthreads();
        // stage chunk c in [kc*32, kc*32+32): thread -> (pos = t>>4, c-pair = t&15)
        {
            int pos = t >> 4, cp = t & 15;
            const float4* src = (const float4*)(X + (pos_base + pos) * 768 + kc * 192) + cp * 3;
            float4 f0 = src[0], f1 = src[1], f2 = src[2];
            u16* bh = sAh + (pos * 6) * SA + cp * 2;
            u16* bl = sAl + (pos * 6) * SA + cp * 2;
            u32 h, l;
            cvt_hilo(f0.x, f1.z, h, l); *(u32*)(bh + 0 * SA) = h; *(u32*)(bl + 0 * SA) = l;
            cvt_hilo(f0.y, f1.w, h, l); *(u32*)(bh + 1 * SA) = h; *(u32*)(bl + 1 * SA) = l;
            cvt_hilo(f0.z, f2.x, h, l); *(u32*)(bh + 2 * SA) = h; *(u32*)(bl + 2 * SA) = l;
            cvt_hilo(f0.w, f2.y, h, l); *(u32*)(bh + 3 * SA) = h; *(u32*)(bl + 3 * SA) = l;
            cvt_hilo(f1.x, f2.z, h, l); *(u32*)(bh + 4 * SA) = h; *(u32*)(bl + 4 * SA) = l;
            cvt_hilo(f1.y, f2.w, h, l); *(u32*)(bh + 5 * SA) = h; *(u32*)(bl + 5 * SA) = l;
        }
        __syncthreads();
        S1_TILE(acc_a, 0) S1_TILE(acc_b, 1) S1_TILE(acc_c, 2) S1_TILE(acc_d, 3) S1_TILE(acc_e, 4)
    }
#undef S1_TILE
    __syncthreads();   // all MFMA reads of sA done before sA2 overlays it

    // ===== fused epilogue: bias + squash (shfl over the 8-lane p-group) + bf16 hi/lo =====
    // C frag: value(row = rt*16+quad*4+r, col = ct*16+m); squash group = cols [g*8, g*8+8)
    // -> lanes differing in m&7 only -> g8sum. Write straight into stage-2 A layout
    // (row' = k*16+pos where row = pos*6+k), no fp32 sS round trip, no squash pass.
#define FUSE_ONE(V)                                                   \
    { float val = (V) + bv;                                           \
      float s2 = g8sum(val * val);                                    \
      float rf = s2 / (1.0f + s2) / (sqrtf(s2) + EPSQ);               \
      float sv = val * rf;                                            \
      __hip_bfloat16 hb = __float2bfloat16(sv);                       \
      float hf = __bfloat162float(hb);                                \
      __hip_bfloat16 lb = __float2bfloat16(sv - hf);                  \
      u16 hu, lu;                                                     \
      __builtin_memcpy(&hu, &hb, 2); __builtin_memcpy(&lu, &lb, 2);   \
      int dr = (kk * 16 + pp) * SA2 + ct * 16 + m;                    \
      sA2h[dr] = hu; sA2l[dr] = lu; }

#define S1_FUSE(ACC, TI)                                              \
    { int T = w + 4 * (TI);                                           \
      if (T < 18) {                                                   \
        int rt = T / 3, ct = T - 3 * rt;                              \
        float bv = bp[ct * 16 + m];                                   \
        int row0 = rt * 16 + quad * 4;                                \
        int pp = row0 / 6, kk = row0 - 6 * pp;                        \
        FUSE_ONE(ACC.x)                                               \
        kk++; if (kk == 6) { kk = 0; pp++; }                          \
        FUSE_ONE(ACC.y)                                               \
        kk++; if (kk == 6) { kk = 0; pp++; }                          \
        FUSE_ONE(ACC.z)                                               \
        kk++; if (kk == 6) { kk = 0; pp++; }                          \
        FUSE_ONE(ACC.w)                                               \
      } }
    S1_FUSE(acc_a, 0) S1_FUSE(acc_b, 1) S1_FUSE(acc_c, 2) S1_FUSE(acc_d, 3) S1_FUSE(acc_e, 4)
#undef S1_FUSE
#undef FUSE_ONE
    __syncthreads();   // sA2 visible to all waves

    // ================= stage 2: u_hat = Xp · W^T, both K-chunks back-to-back ==============
    // chunk 1 covers p=32..63: A cols 48..63 come from the zero block (quad>=2 lanes read
    // the same 16 B -> broadcast, free); B rows 48..63 are zeros from prep.
    floatx4 uacc_a = {0.f,0.f,0.f,0.f}, uacc_b = {0.f,0.f,0.f,0.f}, uacc_c = {0.f,0.f,0.f,0.f},
            uacc_d = {0.f,0.f,0.f,0.f}, uacc_e = {0.f,0.f,0.f,0.f};

#define S2_TILE(ACC, TI)                                                                    \
    { int T = w + 4 * (TI);                                                                 \
      if (T < 18) {                                                                         \
        int k = T / 3, ct = T - 3 * k;                                                      \
        const u16* arh = sA2h + (k * 16 + m) * SA2;                                         \
        const u16* arl = sA2l + (k * 16 + m) * SA2;                                         \
        short8 ah0 = *(const short8*)(arh + quad * 8);                                      \
        short8 al0 = *(const short8*)(arl + quad * 8);                                      \
        const u16* a1h = (quad < 2) ? (arh + 32 + quad * 8) : zpad;                         \
        const u16* a1l = (quad < 2) ? (arl + 32 + quad * 8) : zpad;                         \
        short8 ah1 = *(const short8*)a1h;                                                   \
        short8 al1 = *(const short8*)a1l;                                                   \
        short8 bh0 = *(const short8*)(wf + (((k * 3 + ct) * 2 + 0) * 64 + lane) * 8);       \
        short8 bl0 = *(const short8*)(wf + ((((6 + k) * 3 + ct) * 2 + 0) * 64 + lane) * 8); \
        short8 bh1 = *(const short8*)(wf + (((k * 3 + ct) * 2 + 1) * 64 + lane) * 8);       \
        short8 bl1 = *(const short8*)(wf + ((((6 + k) * 3 + ct) * 2 + 1) * 64 + lane) * 8); \
        ACC = __builtin_amdgcn_mfma_f32_16x16x32_bf16(ah0, bh0, ACC, 0, 0, 0);              \
        ACC = __builtin_amdgcn_mfma_f32_16x16x32_bf16(ah0, bl0, ACC, 0, 0, 0);              \
        ACC = __builtin_amdgcn_mfma_f32_16x16x32_bf16(al0, bh0, ACC, 0, 0, 0);              \
        ACC = __builtin_amdgcn_mfma_f32_16x16x32_bf16(ah1, bh1, ACC, 0, 0, 0);              \
        ACC = __builtin_amdgcn_mfma_f32_16x16x32_bf16(ah1, bl1, ACC, 0, 0, 0);              \
        ACC = __builtin_amdgcn_mfma_f32_16x16x32_bf16(al1, bh1, ACC, 0, 0, 0);              \
      } }
    S2_TILE(uacc_a, 0) S2_TILE(uacc_b, 1) S2_TILE(uacc_c, 2) S2_TILE(uacc_d, 3) S2_TILE(uacc_e, 4)
#undef S2_TILE
    __syncthreads();   // all stage-2 reads of sA2 done before sU overlays it

    // epilogue: C frag -> sU
#define S2_EPI(ACC, TI)                                                   \
    { int T = w + 4 * (TI);                                               \
      if (T < 18) {                                                       \
        int k = T / 3, ct = T - 3 * k;                                    \
        sU[((quad * 4 + 0) * 6 + k) * SS + ct * 16 + m] = ACC.x;          \
        sU[((quad * 4 + 1) * 6 + k) * SS + ct * 16 + m] = ACC.y;          \
        sU[((quad * 4 + 2) * 6 + k) * SS + ct * 16 + m] = ACC.z;          \
        sU[((quad * 4 + 3) * 6 + k) * SS + ct * 16 + m] = ACC.w;          \
      } }
    S2_EPI(uacc_a, 0) S2_EPI(uacc_b, 1) S2_EPI(uacc_c, 2) S2_EPI(uacc_d, 3) S2_EPI(uacc_e, 4)
#undef S2_EPI
    __syncthreads();

    // ================= routing: wave handles 4 positions =================
    const int d = lane >> 4;
    const int q = lane & 15;
    const bool act = (q < 12);
    const int dqi = d * 12 + (act ? q : 0);

    #pragma unroll
    for (int i = 0; i < 4; ++i) {
        int pos = w * 4 + i;
        const float* u = sU + (pos * 6) * SS + dqi;
        float a0 = u[0 * SS], a1 = u[1 * SS], a2 = u[2 * SS];
        float a3 = u[3 * SS], a4 = u[4 * SS], a5 = u[5 * SS];
        if (!act) { a0 = a1 = a2 = a3 = a4 = a5 = 0.f; }
        route_and_write(a0, a1, a2, a3, a4, a5, d, q, act, out, pos_base + pos);
    }
}

extern "C" void kernel_launch(void* const* d_in, const int* in_sizes, int n_in,
                              void* d_out, int out_size, void* d_ws, size_t ws_size,
                              hipStream_t stream) {
    const float* X  = (const float*)d_in[0];   // [64,1024,128,6]
    const float* Wp = (const float*)d_in[1];   // [48,128]
    const float* bp = (const float*)d_in[2];   // [48]
    const float* W  = (const float*)d_in[3];   // [6,4,12,48]
    float* out = (float*)d_out;                // [65536,48]

    u16* wpf = (u16*)d_ws;            // 12288 u16 = 24,576 B
    u16* wf  = wpf + 12288;           // 36864 u16 = 73,728 B  (total 98,304 B of ws)

    hipLaunchKernelGGL(prep_kernel, dim3(48), dim3(256), 0, stream, Wp, W, wpf, wf);

    const int n_pos = 64 * 1024;
    hipLaunchKernelGGL(capsule_kernel, dim3(n_pos / TP), dim3(256), 0, stream,
                       X, bp, wpf, wf, out);
}

// Round 3
// 335.506 us; speedup vs baseline: 1.0570x; 1.0570x over previous
//
#include <hip/hip_runtime.h>
#include <hip/hip_bf16.h>
#include <math.h>

// B=64, L=1024, C=128, K=6, P=6, Dp=8, D=4, Dd=12, ITERS=2
// R2 note: identical to R1 source — R1 bench was an infra failure (container died),
// so this is a straight re-measure of the (256,6) no-spill configuration.
#define EPSQ 1e-9f

typedef float  floatx4 __attribute__((ext_vector_type(4)));
typedef short  short8  __attribute__((ext_vector_type(8)));
typedef unsigned short u16;
typedef unsigned int   u32;

constexpr int TP  = 16;  // positions per block
constexpr int SA  = 40;  // ushort stride, stage-1 A rows (32 data + 8 pad) = 80 B, 16B-aligned
constexpr int SS  = 49;  // dword stride, sU rows (48 data + 1 pad) = 196 B
constexpr int SA2 = 48;  // ushort stride, stage-2 A rows (48 data) = 96 B, 16B-aligned

// LDS plan (single overlaid region, phases separated by barriers):
//   phase 1: sA   = [96][SA] u16 hi + lo           = 15,360 B   (stage-1 X staging)
//   phase 2: sA2  = [96][SA2] u16 hi + lo          = 18,432 B   (stage-2 A fragments, written from regs)
//   phase 3: sU   = [96][SS] f32                   = 18,816 B   (u_hat for routing)
//   + 32 B zero block at 18,816 for quad>=2 chunk-1 A-fragment reads
// total 18,848 B.
// R1 lesson: __launch_bounds__(256,8) (64-reg cap) forced ~240 MB of scratch spill
// (WRITE_SIZE 12->123 MB, VGPR_Count 32). Use (256,6): 85-reg cap, no spill, LDS still
// admits 8 blocks/CU; VGPR becomes the occupancy limiter at ~6-7 waves/SIMD.

// fp32 -> (hi, lo) bf16 pair-packed as u32 (2 elements per call)
__device__ __forceinline__ void cvt_hilo(float a, float b, u32& hi, u32& lo) {
    __hip_bfloat162 h = __float22bfloat162_rn(make_float2(a, b));
    float2 hf = __bfloat1622float2(h);
    __hip_bfloat162 l = __float22bfloat162_rn(make_float2(a - hf.x, b - hf.y));
    __builtin_memcpy(&hi, &h, 4);
    __builtin_memcpy(&lo, &l, 4);
}

__device__ __forceinline__ float g16sum(float x) {
    x += __shfl_xor(x, 1);
    x += __shfl_xor(x, 2);
    x += __shfl_xor(x, 4);
    x += __shfl_xor(x, 8);
    return x;
}

__device__ __forceinline__ float g8sum(float x) {
    x += __shfl_xor(x, 1);
    x += __shfl_xor(x, 2);
    x += __shfl_xor(x, 4);
    return x;
}

// Dynamic routing (ITERS=2), named scalars only (R4 lesson: no local arrays).
__device__ __forceinline__ void route_and_write(float u0, float u1, float u2,
                                                float u3, float u4, float u5,
                                                int d, int q, bool act,
                                                float* __restrict__ out, long pos)
{
    float s = (u0 + u1 + u2 + u3 + u4 + u5) * 0.25f;
    float s2 = g16sum(s * s);
    float v = s * (s2 / (1.0f + s2) / (sqrtf(s2) + EPSQ));

    float ss = 0.f;
#define ROUTE_K(UK)                                        \
    {                                                      \
        float b = g16sum((UK) * v);                        \
        float mm = fmaxf(b, __shfl_xor(b, 16));            \
        mm = fmaxf(mm, __shfl_xor(mm, 32));                \
        float e = __expf(b - mm);                          \
        float es = e + __shfl_xor(e, 16);                  \
        es += __shfl_xor(es, 32);                          \
        ss = fmaf(e / es, (UK), ss);                       \
    }
    ROUTE_K(u0) ROUTE_K(u1) ROUTE_K(u2) ROUTE_K(u3) ROUTE_K(u4) ROUTE_K(u5)
#undef ROUTE_K
    float ss2 = g16sum(ss * ss);
    float vv = ss * (ss2 / (1.0f + ss2) / (sqrtf(ss2) + EPSQ));
    if (act) out[pos * 48 + d * 12 + q] = vv;
}

// ---- prep: convert Wp/W into MFMA-B-fragment-ready bf16 hi/lo layouts in ws. (UNCHANGED)
// wpf: [var2][ct3][kc4][lane64][j8]  = Wp[p=ct*16+(lane&15)][c=kc*32+quad*8+j]
// wf : [var2][k6][ct3][kc2][lane64][j8] = W[k][dq=ct*16+(lane&15)][p=kc*32+quad*8+j], 0 if p>=48
__global__ void prep_kernel(const float* __restrict__ Wp, const float* __restrict__ W,
                            u16* __restrict__ wpf, u16* __restrict__ wf) {
    int gid = blockIdx.x * 256 + threadIdx.x;
    int stride = gridDim.x * 256;
    for (int i = gid; i < 12288; i += stride) {
        int j = i & 7, lane = (i >> 3) & 63, kc = (i >> 9) & 3, vt = i >> 11;
        int var = (vt >= 3) ? 1 : 0;
        int ct = vt - 3 * var;
        int p = ct * 16 + (lane & 15);
        int c = kc * 32 + (lane >> 4) * 8 + j;
        float x = Wp[p * 128 + c];
        __hip_bfloat16 hb = __float2bfloat16(x);
        if (var) { float hf = __bfloat162float(hb); hb = __float2bfloat16(x - hf); }
        u16 u; __builtin_memcpy(&u, &hb, 2);
        wpf[i] = u;
    }
    for (int i = gid; i < 36864; i += stride) {
        int j = i & 7, lane = (i >> 3) & 63, kc = (i >> 9) & 1, q3 = i >> 10;
        int ct = q3 % 3, kk = q3 / 3;       // kk = var*6 + k
        int k = kk % 6, var = kk / 6;
        int dq = ct * 16 + (lane & 15);
        int p = kc * 32 + (lane >> 4) * 8 + j;
        float x = (p < 48) ? W[(k * 48 + dq) * 48 + p] : 0.f;
        __hip_bfloat16 hb = __float2bfloat16(x);
        if (var) { float hf = __bfloat162float(hb); hb = __float2bfloat16(x - hf); }
        u16 u; __builtin_memcpy(&u, &hb, 2);
        wf[i] = u;
    }
}

__global__ __launch_bounds__(256, 6)
void capsule_kernel(
    const float* __restrict__ X,    // [65536][128][6]
    const float* __restrict__ bp,   // [48]
    const u16* __restrict__ wpf,    // prepped Wp fragments
    const u16* __restrict__ wf,     // prepped W fragments
    float* __restrict__ out)        // [65536][48]
{
    __shared__ __align__(16) char raw[18848];
    u16*   sAh  = (u16*)raw;                 // [96][SA]  (phase 1)
    u16*   sAl  = sAh + 96 * SA;
    u16*   sA2h = (u16*)raw;                 // [96][SA2] (phase 2, overlays sA)
    u16*   sA2l = sA2h + 96 * SA2;
    float* sU   = (float*)raw;               // [96][SS]  (phase 3, overlays sA2)
    const u16* zpad = (const u16*)(raw + 18816);  // 32 B of zeros

    const int t    = threadIdx.x;
    const int lane = t & 63;
    const int w    = t >> 6;
    const int m    = lane & 15;
    const int quad = lane >> 4;
    const long pos_base = (long)blockIdx.x * TP;

    if (t < 8) ((u32*)(raw + 18816))[t] = 0u;   // zero block, visible after first barrier

    // ================= stage 1: projection  acc[(pos*6+k)][p] = X·Wp^T (+bp later) ==========
    floatx4 acc_a = {0.f,0.f,0.f,0.f}, acc_b = {0.f,0.f,0.f,0.f}, acc_c = {0.f,0.f,0.f,0.f},
            acc_d = {0.f,0.f,0.f,0.f}, acc_e = {0.f,0.f,0.f,0.f};

#define S1_TILE(ACC, TI)                                                              \
    { int T = w + 4 * (TI);                                                           \
      if (T < 18) {                                                                   \
        int rt = T / 3, ct = T - 3 * rt;                                              \
        short8 ah = *(const short8*)(sAh + (rt * 16 + m) * SA + quad * 8);            \
        short8 al = *(const short8*)(sAl + (rt * 16 + m) * SA + quad * 8);            \
        short8 bh = *(const short8*)(wpf + ((ct * 4 + kc) * 64 + lane) * 8);          \
        short8 bl = *(const short8*)(wpf + (((3 + ct) * 4 + kc) * 64 + lane) * 8);    \
        ACC = __builtin_amdgcn_mfma_f32_16x16x32_bf16(ah, bh, ACC, 0, 0, 0);          \
        ACC = __builtin_amdgcn_mfma_f32_16x16x32_bf16(ah, bl, ACC, 0, 0, 0);          \
        ACC = __builtin_amdgcn_mfma_f32_16x16x32_bf16(al, bh, ACC, 0, 0, 0);          \
      } }

    #pragma unroll
    for (int kc = 0; kc < 4; ++kc) {
        if (kc > 0) __syncthreads();
        // stage chunk c in [kc*32, kc*32+32): thread -> (pos = t>>4, c-pair = t&15)
        {
            int pos = t >> 4, cp = t & 15;
            const float4* src = (const float4*)(X + (pos_base + pos) * 768 + kc * 192) + cp * 3;
            float4 f0 = src[0], f1 = src[1], f2 = src[2];
            u16* bh = sAh + (pos * 6) * SA + cp * 2;
            u16* bl = sAl + (pos * 6) * SA + cp * 2;
            u32 h, l;
            cvt_hilo(f0.x, f1.z, h, l); *(u32*)(bh + 0 * SA) = h; *(u32*)(bl + 0 * SA) = l;
            cvt_hilo(f0.y, f1.w, h, l); *(u32*)(bh + 1 * SA) = h; *(u32*)(bl + 1 * SA) = l;
            cvt_hilo(f0.z, f2.x, h, l); *(u32*)(bh + 2 * SA) = h; *(u32*)(bl + 2 * SA) = l;
            cvt_hilo(f0.w, f2.y, h, l); *(u32*)(bh + 3 * SA) = h; *(u32*)(bl + 3 * SA) = l;
            cvt_hilo(f1.x, f2.z, h, l); *(u32*)(bh + 4 * SA) = h; *(u32*)(bl + 4 * SA) = l;
            cvt_hilo(f1.y, f2.w, h, l); *(u32*)(bh + 5 * SA) = h; *(u32*)(bl + 5 * SA) = l;
        }
        __syncthreads();
        S1_TILE(acc_a, 0) S1_TILE(acc_b, 1) S1_TILE(acc_c, 2) S1_TILE(acc_d, 3) S1_TILE(acc_e, 4)
    }
#undef S1_TILE
    __syncthreads();   // all MFMA reads of sA done before sA2 overlays it

    // ===== fused epilogue: bias + squash (shfl over the 8-lane p-group) + bf16 hi/lo =====
    // C frag: value(row = rt*16+quad*4+r, col = ct*16+m); squash group = cols [g*8, g*8+8)
    // -> lanes differing in m&7 only -> g8sum. Write straight into stage-2 A layout
    // (row' = k*16+pos where row = pos*6+k), no fp32 sS round trip, no squash pass.
#define FUSE_ONE(V)                                                   \
    { float val = (V) + bv;                                           \
      float s2 = g8sum(val * val);                                    \
      float rf = s2 / (1.0f + s2) / (sqrtf(s2) + EPSQ);               \
      float sv = val * rf;                                            \
      __hip_bfloat16 hb = __float2bfloat16(sv);                       \
      float hf = __bfloat162float(hb);                                \
      __hip_bfloat16 lb = __float2bfloat16(sv - hf);                  \
      u16 hu, lu;                                                     \
      __builtin_memcpy(&hu, &hb, 2); __builtin_memcpy(&lu, &lb, 2);   \
      int dr = (kk * 16 + pp) * SA2 + ct * 16 + m;                    \
      sA2h[dr] = hu; sA2l[dr] = lu; }

#define S1_FUSE(ACC, TI)                                              \
    { int T = w + 4 * (TI);                                           \
      if (T < 18) {                                                   \
        int rt = T / 3, ct = T - 3 * rt;                              \
        float bv = bp[ct * 16 + m];                                   \
        int row0 = rt * 16 + quad * 4;                                \
        int pp = row0 / 6, kk = row0 - 6 * pp;                        \
        FUSE_ONE(ACC.x)                                               \
        kk++; if (kk == 6) { kk = 0; pp++; }                          \
        FUSE_ONE(ACC.y)                                               \
        kk++; if (kk == 6) { kk = 0; pp++; }                          \
        FUSE_ONE(ACC.z)                                               \
        kk++; if (kk == 6) { kk = 0; pp++; }                          \
        FUSE_ONE(ACC.w)                                               \
      } }
    S1_FUSE(acc_a, 0) S1_FUSE(acc_b, 1) S1_FUSE(acc_c, 2) S1_FUSE(acc_d, 3) S1_FUSE(acc_e, 4)
#undef S1_FUSE
#undef FUSE_ONE
    __syncthreads();   // sA2 visible to all waves

    // ================= stage 2: u_hat = Xp · W^T, both K-chunks back-to-back ==============
    // chunk 1 covers p=32..63: A cols 48..63 come from the zero block (quad>=2 lanes read
    // the same 16 B -> broadcast, free); B rows 48..63 are zeros from prep.
    // Chunk 0 is fully consumed before chunk 1's fragments are loaded (peak live
    // fragments ~8 regs instead of 16 -> fits the 85-reg budget without spill).
    floatx4 uacc_a = {0.f,0.f,0.f,0.f}, uacc_b = {0.f,0.f,0.f,0.f}, uacc_c = {0.f,0.f,0.f,0.f},
            uacc_d = {0.f,0.f,0.f,0.f}, uacc_e = {0.f,0.f,0.f,0.f};

#define S2_TILE(ACC, TI)                                                                      \
    { int T = w + 4 * (TI);                                                                   \
      if (T < 18) {                                                                           \
        int k = T / 3, ct = T - 3 * k;                                                        \
        const u16* arh = sA2h + (k * 16 + m) * SA2;                                           \
        const u16* arl = sA2l + (k * 16 + m) * SA2;                                           \
        {                                                                                     \
          short8 ah0 = *(const short8*)(arh + quad * 8);                                      \
          short8 al0 = *(const short8*)(arl + quad * 8);                                      \
          short8 bh0 = *(const short8*)(wf + (((k * 3 + ct) * 2 + 0) * 64 + lane) * 8);       \
          short8 bl0 = *(const short8*)(wf + ((((6 + k) * 3 + ct) * 2 + 0) * 64 + lane) * 8); \
          ACC = __builtin_amdgcn_mfma_f32_16x16x32_bf16(ah0, bh0, ACC, 0, 0, 0);              \
          ACC = __builtin_amdgcn_mfma_f32_16x16x32_bf16(ah0, bl0, ACC, 0, 0, 0);              \
          ACC = __builtin_amdgcn_mfma_f32_16x16x32_bf16(al0, bh0, ACC, 0, 0, 0);              \
        }                                                                                     \
        {                                                                                     \
          const u16* a1h = (quad < 2) ? (arh + 32 + quad * 8) : zpad;                         \
          const u16* a1l = (quad < 2) ? (arl + 32 + quad * 8) : zpad;                         \
          short8 ah1 = *(const short8*)a1h;                                                   \
          short8 al1 = *(const short8*)a1l;                                                   \
          short8 bh1 = *(const short8*)(wf + (((k * 3 + ct) * 2 + 1) * 64 + lane) * 8);       \
          short8 bl1 = *(const short8*)(wf + ((((6 + k) * 3 + ct) * 2 + 1) * 64 + lane) * 8); \
          ACC = __builtin_amdgcn_mfma_f32_16x16x32_bf16(ah1, bh1, ACC, 0, 0, 0);              \
          ACC = __builtin_amdgcn_mfma_f32_16x16x32_bf16(ah1, bl1, ACC, 0, 0, 0);              \
          ACC = __builtin_amdgcn_mfma_f32_16x16x32_bf16(al1, bh1, ACC, 0, 0, 0);              \
        }                                                                                     \
      } }
    S2_TILE(uacc_a, 0) S2_TILE(uacc_b, 1) S2_TILE(uacc_c, 2) S2_TILE(uacc_d, 3) S2_TILE(uacc_e, 4)
#undef S2_TILE
    __syncthreads();   // all stage-2 reads of sA2 done before sU overlays it

    // epilogue: C frag -> sU
#define S2_EPI(ACC, TI)                                                   \
    { int T = w + 4 * (TI);                                               \
      if (T < 18) {                                                       \
        int k = T / 3, ct = T - 3 * k;                                    \
        sU[((quad * 4 + 0) * 6 + k) * SS + ct * 16 + m] = ACC.x;          \
        sU[((quad * 4 + 1) * 6 + k) * SS + ct * 16 + m] = ACC.y;          \
        sU[((quad * 4 + 2) * 6 + k) * SS + ct * 16 + m] = ACC.z;          \
        sU[((quad * 4 + 3) * 6 + k) * SS + ct * 16 + m] = ACC.w;          \
      } }
    S2_EPI(uacc_a, 0) S2_EPI(uacc_b, 1) S2_EPI(uacc_c, 2) S2_EPI(uacc_d, 3) S2_EPI(uacc_e, 4)
#undef S2_EPI
    __syncthreads();

    // ================= routing: wave handles 4 positions =================
    const int d = lane >> 4;
    const int q = lane & 15;
    const bool act = (q < 12);
    const int dqi = d * 12 + (act ? q : 0);

    #pragma unroll
    for (int i = 0; i < 4; ++i) {
        int pos = w * 4 + i;
        const float* u = sU + (pos * 6) * SS + dqi;
        float a0 = u[0 * SS], a1 = u[1 * SS], a2 = u[2 * SS];
        float a3 = u[3 * SS], a4 = u[4 * SS], a5 = u[5 * SS];
        if (!act) { a0 = a1 = a2 = a3 = a4 = a5 = 0.f; }
        route_and_write(a0, a1, a2, a3, a4, a5, d, q, act, out, pos_base + pos);
    }
}

extern "C" void kernel_launch(void* const* d_in, const int* in_sizes, int n_in,
                              void* d_out, int out_size, void* d_ws, size_t ws_size,
                              hipStream_t stream) {
    const float* X  = (const float*)d_in[0];   // [64,1024,128,6]
    const float* Wp = (const float*)d_in[1];   // [48,128]
    const float* bp = (const float*)d_in[2];   // [48]
    const float* W  = (const float*)d_in[3];   // [6,4,12,48]
    float* out = (float*)d_out;                // [65536,48]

    u16* wpf = (u16*)d_ws;            // 12288 u16 = 24,576 B
    u16* wf  = wpf + 12288;           // 36864 u16 = 73,728 B  (total 98,304 B of ws)

    hipLaunchKernelGGL(prep_kernel, dim3(48), dim3(256), 0, stream, Wp, W, wpf, wf);

    const int n_pos = 64 * 1024;
    hipLaunchKernelGGL(capsule_kernel, dim3(n_pos / TP), dim3(256), 0, stream,
                       X, bp, wpf, wf, out);
}

// Round 4
// 329.961 us; speedup vs baseline: 1.0748x; 1.0168x over previous
//
#include <hip/hip_runtime.h>
#include <hip/hip_bf16.h>
#include <math.h>

// B=64, L=1024, C=128, K=6, P=6, Dp=8, D=4, Dd=12, ITERS=2
// R3 lesson: kernel is VALU-issue-bound (VALUBusy 56%, MfmaUtil 6.5%, HBM 10%).
// ~5,800 VALU insts/wave; ~1,000 of them are IEEE div/sqrt expansions (no -ffast-math).
// R4 change: route all squash/softmax div+sqrt through v_rcp_f32/v_sqrt_f32
// (__builtin_amdgcn_rcpf / __builtin_amdgcn_sqrtf, ~1 ulp — invisible vs 2^-9 absmax).
#define EPSQ 1e-9f

typedef float  floatx4 __attribute__((ext_vector_type(4)));
typedef short  short8  __attribute__((ext_vector_type(8)));
typedef unsigned short u16;
typedef unsigned int   u32;

constexpr int TP  = 16;  // positions per block
constexpr int SA  = 40;  // ushort stride, stage-1 A rows (32 data + 8 pad) = 80 B, 16B-aligned
constexpr int SS  = 49;  // dword stride, sU rows (48 data + 1 pad) = 196 B
constexpr int SA2 = 48;  // ushort stride, stage-2 A rows (48 data) = 96 B, 16B-aligned

// LDS plan (single overlaid region, phases separated by barriers):
//   phase 1: sA   = [96][SA] u16 hi + lo           = 15,360 B   (stage-1 X staging)
//   phase 2: sA2  = [96][SA2] u16 hi + lo          = 18,432 B   (stage-2 A fragments, written from regs)
//   phase 3: sU   = [96][SS] f32                   = 18,816 B   (u_hat for routing)
//   + 32 B zero block at 18,816 for quad>=2 chunk-1 A-fragment reads
// total 18,848 B.
// R1 lesson: __launch_bounds__(256,8) (64-reg cap) forced ~240 MB of scratch spill
// (WRITE_SIZE 12->123 MB, VGPR_Count 32). Use (256,6): 85-reg cap, no spill.

// fast ~1-ulp hardware approximations (v_rcp_f32 / v_sqrt_f32)
__device__ __forceinline__ float fast_rcp(float x)  { return __builtin_amdgcn_rcpf(x); }
__device__ __forceinline__ float fast_sqrt(float x) { return __builtin_amdgcn_sqrtf(x); }

// squash scale factor: s2/(1+s2)/(sqrt(s2)+eps), all-approx (2 rcp + 1 sqrt + 3 mul/add)
__device__ __forceinline__ float squash_rf(float s2) {
    return s2 * fast_rcp(1.0f + s2) * fast_rcp(fast_sqrt(s2) + EPSQ);
}

// fp32 -> (hi, lo) bf16 pair-packed as u32 (2 elements per call)
__device__ __forceinline__ void cvt_hilo(float a, float b, u32& hi, u32& lo) {
    __hip_bfloat162 h = __float22bfloat162_rn(make_float2(a, b));
    float2 hf = __bfloat1622float2(h);
    __hip_bfloat162 l = __float22bfloat162_rn(make_float2(a - hf.x, b - hf.y));
    __builtin_memcpy(&hi, &h, 4);
    __builtin_memcpy(&lo, &l, 4);
}

__device__ __forceinline__ float g16sum(float x) {
    x += __shfl_xor(x, 1);
    x += __shfl_xor(x, 2);
    x += __shfl_xor(x, 4);
    x += __shfl_xor(x, 8);
    return x;
}

__device__ __forceinline__ float g8sum(float x) {
    x += __shfl_xor(x, 1);
    x += __shfl_xor(x, 2);
    x += __shfl_xor(x, 4);
    return x;
}

// Dynamic routing (ITERS=2), named scalars only (R4 lesson: no local arrays).
__device__ __forceinline__ void route_and_write(float u0, float u1, float u2,
                                                float u3, float u4, float u5,
                                                int d, int q, bool act,
                                                float* __restrict__ out, long pos)
{
    float s = (u0 + u1 + u2 + u3 + u4 + u5) * 0.25f;
    float s2 = g16sum(s * s);
    float v = s * squash_rf(s2);

    float ss = 0.f;
#define ROUTE_K(UK)                                        \
    {                                                      \
        float b = g16sum((UK) * v);                        \
        float mm = fmaxf(b, __shfl_xor(b, 16));            \
        mm = fmaxf(mm, __shfl_xor(mm, 32));                \
        float e = __expf(b - mm);                          \
        float es = e + __shfl_xor(e, 16);                  \
        es += __shfl_xor(es, 32);                          \
        ss = fmaf(e * fast_rcp(es), (UK), ss);             \
    }
    ROUTE_K(u0) ROUTE_K(u1) ROUTE_K(u2) ROUTE_K(u3) ROUTE_K(u4) ROUTE_K(u5)
#undef ROUTE_K
    float ss2 = g16sum(ss * ss);
    float vv = ss * squash_rf(ss2);
    if (act) out[pos * 48 + d * 12 + q] = vv;
}

// ---- prep: convert Wp/W into MFMA-B-fragment-ready bf16 hi/lo layouts in ws. (UNCHANGED)
// wpf: [var2][ct3][kc4][lane64][j8]  = Wp[p=ct*16+(lane&15)][c=kc*32+quad*8+j]
// wf : [var2][k6][ct3][kc2][lane64][j8] = W[k][dq=ct*16+(lane&15)][p=kc*32+quad*8+j], 0 if p>=48
__global__ void prep_kernel(const float* __restrict__ Wp, const float* __restrict__ W,
                            u16* __restrict__ wpf, u16* __restrict__ wf) {
    int gid = blockIdx.x * 256 + threadIdx.x;
    int stride = gridDim.x * 256;
    for (int i = gid; i < 12288; i += stride) {
        int j = i & 7, lane = (i >> 3) & 63, kc = (i >> 9) & 3, vt = i >> 11;
        int var = (vt >= 3) ? 1 : 0;
        int ct = vt - 3 * var;
        int p = ct * 16 + (lane & 15);
        int c = kc * 32 + (lane >> 4) * 8 + j;
        float x = Wp[p * 128 + c];
        __hip_bfloat16 hb = __float2bfloat16(x);
        if (var) { float hf = __bfloat162float(hb); hb = __float2bfloat16(x - hf); }
        u16 u; __builtin_memcpy(&u, &hb, 2);
        wpf[i] = u;
    }
    for (int i = gid; i < 36864; i += stride) {
        int j = i & 7, lane = (i >> 3) & 63, kc = (i >> 9) & 1, q3 = i >> 10;
        int ct = q3 % 3, kk = q3 / 3;       // kk = var*6 + k
        int k = kk % 6, var = kk / 6;
        int dq = ct * 16 + (lane & 15);
        int p = kc * 32 + (lane >> 4) * 8 + j;
        float x = (p < 48) ? W[(k * 48 + dq) * 48 + p] : 0.f;
        __hip_bfloat16 hb = __float2bfloat16(x);
        if (var) { float hf = __bfloat162float(hb); hb = __float2bfloat16(x - hf); }
        u16 u; __builtin_memcpy(&u, &hb, 2);
        wf[i] = u;
    }
}

__global__ __launch_bounds__(256, 6)
void capsule_kernel(
    const float* __restrict__ X,    // [65536][128][6]
    const float* __restrict__ bp,   // [48]
    const u16* __restrict__ wpf,    // prepped Wp fragments
    const u16* __restrict__ wf,     // prepped W fragments
    float* __restrict__ out)        // [65536][48]
{
    __shared__ __align__(16) char raw[18848];
    u16*   sAh  = (u16*)raw;                 // [96][SA]  (phase 1)
    u16*   sAl  = sAh + 96 * SA;
    u16*   sA2h = (u16*)raw;                 // [96][SA2] (phase 2, overlays sA)
    u16*   sA2l = sA2h + 96 * SA2;
    float* sU   = (float*)raw;               // [96][SS]  (phase 3, overlays sA2)
    const u16* zpad = (const u16*)(raw + 18816);  // 32 B of zeros

    const int t    = threadIdx.x;
    const int lane = t & 63;
    const int w    = t >> 6;
    const int m    = lane & 15;
    const int quad = lane >> 4;
    const long pos_base = (long)blockIdx.x * TP;

    if (t < 8) ((u32*)(raw + 18816))[t] = 0u;   // zero block, visible after first barrier

    // ================= stage 1: projection  acc[(pos*6+k)][p] = X·Wp^T (+bp later) ==========
    floatx4 acc_a = {0.f,0.f,0.f,0.f}, acc_b = {0.f,0.f,0.f,0.f}, acc_c = {0.f,0.f,0.f,0.f},
            acc_d = {0.f,0.f,0.f,0.f}, acc_e = {0.f,0.f,0.f,0.f};

#define S1_TILE(ACC, TI)                                                              \
    { int T = w + 4 * (TI);                                                           \
      if (T < 18) {                                                                   \
        int rt = T / 3, ct = T - 3 * rt;                                              \
        short8 ah = *(const short8*)(sAh + (rt * 16 + m) * SA + quad * 8);            \
        short8 al = *(const short8*)(sAl + (rt * 16 + m) * SA + quad * 8);            \
        short8 bh = *(const short8*)(wpf + ((ct * 4 + kc) * 64 + lane) * 8);          \
        short8 bl = *(const short8*)(wpf + (((3 + ct) * 4 + kc) * 64 + lane) * 8);    \
        ACC = __builtin_amdgcn_mfma_f32_16x16x32_bf16(ah, bh, ACC, 0, 0, 0);          \
        ACC = __builtin_amdgcn_mfma_f32_16x16x32_bf16(ah, bl, ACC, 0, 0, 0);          \
        ACC = __builtin_amdgcn_mfma_f32_16x16x32_bf16(al, bh, ACC, 0, 0, 0);          \
      } }

    #pragma unroll
    for (int kc = 0; kc < 4; ++kc) {
        if (kc > 0) __syncthreads();
        // stage chunk c in [kc*32, kc*32+32): thread -> (pos = t>>4, c-pair = t&15)
        {
            int pos = t >> 4, cp = t & 15;
            const float4* src = (const float4*)(X + (pos_base + pos) * 768 + kc * 192) + cp * 3;
            float4 f0 = src[0], f1 = src[1], f2 = src[2];
            u16* bh = sAh + (pos * 6) * SA + cp * 2;
            u16* bl = sAl + (pos * 6) * SA + cp * 2;
            u32 h, l;
            cvt_hilo(f0.x, f1.z, h, l); *(u32*)(bh + 0 * SA) = h; *(u32*)(bl + 0 * SA) = l;
            cvt_hilo(f0.y, f1.w, h, l); *(u32*)(bh + 1 * SA) = h; *(u32*)(bl + 1 * SA) = l;
            cvt_hilo(f0.z, f2.x, h, l); *(u32*)(bh + 2 * SA) = h; *(u32*)(bl + 2 * SA) = l;
            cvt_hilo(f0.w, f2.y, h, l); *(u32*)(bh + 3 * SA) = h; *(u32*)(bl + 3 * SA) = l;
            cvt_hilo(f1.x, f2.z, h, l); *(u32*)(bh + 4 * SA) = h; *(u32*)(bl + 4 * SA) = l;
            cvt_hilo(f1.y, f2.w, h, l); *(u32*)(bh + 5 * SA) = h; *(u32*)(bl + 5 * SA) = l;
        }
        __syncthreads();
        S1_TILE(acc_a, 0) S1_TILE(acc_b, 1) S1_TILE(acc_c, 2) S1_TILE(acc_d, 3) S1_TILE(acc_e, 4)
    }
#undef S1_TILE
    __syncthreads();   // all MFMA reads of sA done before sA2 overlays it

    // ===== fused epilogue: bias + squash (shfl over the 8-lane p-group) + bf16 hi/lo =====
    // C frag: value(row = rt*16+quad*4+r, col = ct*16+m); squash group = cols [g*8, g*8+8)
    // -> lanes differing in m&7 only -> g8sum. Write straight into stage-2 A layout
    // (row' = k*16+pos where row = pos*6+k), no fp32 sS round trip, no squash pass.
#define FUSE_ONE(V)                                                   \
    { float val = (V) + bv;                                           \
      float s2 = g8sum(val * val);                                    \
      float sv = val * squash_rf(s2);                                 \
      __hip_bfloat16 hb = __float2bfloat16(sv);                       \
      float hf = __bfloat162float(hb);                                \
      __hip_bfloat16 lb = __float2bfloat16(sv - hf);                  \
      u16 hu, lu;                                                     \
      __builtin_memcpy(&hu, &hb, 2); __builtin_memcpy(&lu, &lb, 2);   \
      int dr = (kk * 16 + pp) * SA2 + ct * 16 + m;                    \
      sA2h[dr] = hu; sA2l[dr] = lu; }

#define S1_FUSE(ACC, TI)                                              \
    { int T = w + 4 * (TI);                                           \
      if (T < 18) {                                                   \
        int rt = T / 3, ct = T - 3 * rt;                              \
        float bv = bp[ct * 16 + m];                                   \
        int row0 = rt * 16 + quad * 4;                                \
        int pp = row0 / 6, kk = row0 - 6 * pp;                        \
        FUSE_ONE(ACC.x)                                               \
        kk++; if (kk == 6) { kk = 0; pp++; }                          \
        FUSE_ONE(ACC.y)                                               \
        kk++; if (kk == 6) { kk = 0; pp++; }                          \
        FUSE_ONE(ACC.z)                                               \
        kk++; if (kk == 6) { kk = 0; pp++; }                          \
        FUSE_ONE(ACC.w)                                               \
      } }
    S1_FUSE(acc_a, 0) S1_FUSE(acc_b, 1) S1_FUSE(acc_c, 2) S1_FUSE(acc_d, 3) S1_FUSE(acc_e, 4)
#undef S1_FUSE
#undef FUSE_ONE
    __syncthreads();   // sA2 visible to all waves

    // ================= stage 2: u_hat = Xp · W^T, both K-chunks back-to-back ==============
    // chunk 1 covers p=32..63: A cols 48..63 come from the zero block (quad>=2 lanes read
    // the same 16 B -> broadcast, free); B rows 48..63 are zeros from prep.
    // Chunk 0 is fully consumed before chunk 1's fragments are loaded (peak live
    // fragments ~8 regs instead of 16 -> fits the 85-reg budget without spill).
    floatx4 uacc_a = {0.f,0.f,0.f,0.f}, uacc_b = {0.f,0.f,0.f,0.f}, uacc_c = {0.f,0.f,0.f,0.f},
            uacc_d = {0.f,0.f,0.f,0.f}, uacc_e = {0.f,0.f,0.f,0.f};

#define S2_TILE(ACC, TI)                                                                      \
    { int T = w + 4 * (TI);                                                                   \
      if (T < 18) {                                                                           \
        int k = T / 3, ct = T - 3 * k;                                                        \
        const u16* arh = sA2h + (k * 16 + m) * SA2;                                           \
        const u16* arl = sA2l + (k * 16 + m) * SA2;                                           \
        {                                                                                     \
          short8 ah0 = *(const short8*)(arh + quad * 8);                                      \
          short8 al0 = *(const short8*)(arl + quad * 8);                                      \
          short8 bh0 = *(const short8*)(wf + (((k * 3 + ct) * 2 + 0) * 64 + lane) * 8);       \
          short8 bl0 = *(const short8*)(wf + ((((6 + k) * 3 + ct) * 2 + 0) * 64 + lane) * 8); \
          ACC = __builtin_amdgcn_mfma_f32_16x16x32_bf16(ah0, bh0, ACC, 0, 0, 0);              \
          ACC = __builtin_amdgcn_mfma_f32_16x16x32_bf16(ah0, bl0, ACC, 0, 0, 0);              \
          ACC = __builtin_amdgcn_mfma_f32_16x16x32_bf16(al0, bh0, ACC, 0, 0, 0);              \
        }                                                                                     \
        {                                                                                     \
          const u16* a1h = (quad < 2) ? (arh + 32 + quad * 8) : zpad;                         \
          const u16* a1l = (quad < 2) ? (arl + 32 + quad * 8) : zpad;                         \
          short8 ah1 = *(const short8*)a1h;                                                   \
          short8 al1 = *(const short8*)a1l;                                                   \
          short8 bh1 = *(const short8*)(wf + (((k * 3 + ct) * 2 + 1) * 64 + lane) * 8);       \
          short8 bl1 = *(const short8*)(wf + ((((6 + k) * 3 + ct) * 2 + 1) * 64 + lane) * 8); \
          ACC = __builtin_amdgcn_mfma_f32_16x16x32_bf16(ah1, bh1, ACC, 0, 0, 0);              \
          ACC = __builtin_amdgcn_mfma_f32_16x16x32_bf16(ah1, bl1, ACC, 0, 0, 0);              \
          ACC = __builtin_amdgcn_mfma_f32_16x16x32_bf16(al1, bh1, ACC, 0, 0, 0);              \
        }                                                                                     \
      } }
    S2_TILE(uacc_a, 0) S2_TILE(uacc_b, 1) S2_TILE(uacc_c, 2) S2_TILE(uacc_d, 3) S2_TILE(uacc_e, 4)
#undef S2_TILE
    __syncthreads();   // all stage-2 reads of sA2 done before sU overlays it

    // epilogue: C frag -> sU
#define S2_EPI(ACC, TI)                                                   \
    { int T = w + 4 * (TI);                                               \
      if (T < 18) {                                                       \
        int k = T / 3, ct = T - 3 * k;                                    \
        sU[((quad * 4 + 0) * 6 + k) * SS + ct * 16 + m] = ACC.x;          \
        sU[((quad * 4 + 1) * 6 + k) * SS + ct * 16 + m] = ACC.y;          \
        sU[((quad * 4 + 2) * 6 + k) * SS + ct * 16 + m] = ACC.z;          \
        sU[((quad * 4 + 3) * 6 + k) * SS + ct * 16 + m] = ACC.w;          \
      } }
    S2_EPI(uacc_a, 0) S2_EPI(uacc_b, 1) S2_EPI(uacc_c, 2) S2_EPI(uacc_d, 3) S2_EPI(uacc_e, 4)
#undef S2_EPI
    __syncthreads();

    // ================= routing: wave handles 4 positions =================
    const int d = lane >> 4;
    const int q = lane & 15;
    const bool act = (q < 12);
    const int dqi = d * 12 + (act ? q : 0);

    #pragma unroll
    for (int i = 0; i < 4; ++i) {
        int pos = w * 4 + i;
        const float* u = sU + (pos * 6) * SS + dqi;
        float a0 = u[0 * SS], a1 = u[1 * SS], a2 = u[2 * SS];
        float a3 = u[3 * SS], a4 = u[4 * SS], a5 = u[5 * SS];
        if (!act) { a0 = a1 = a2 = a3 = a4 = a5 = 0.f; }
        route_and_write(a0, a1, a2, a3, a4, a5, d, q, act, out, pos_base + pos);
    }
}

extern "C" void kernel_launch(void* const* d_in, const int* in_sizes, int n_in,
                              void* d_out, int out_size, void* d_ws, size_t ws_size,
                              hipStream_t stream) {
    const float* X  = (const float*)d_in[0];   // [64,1024,128,6]
    const float* Wp = (const float*)d_in[1];   // [48,128]
    const float* bp = (const float*)d_in[2];   // [48]
    const float* W  = (const float*)d_in[3];   // [6,4,12,48]
    float* out = (float*)d_out;                // [65536,48]

    u16* wpf = (u16*)d_ws;            // 12288 u16 = 24,576 B
    u16* wf  = wpf + 12288;           // 36864 u16 = 73,728 B  (total 98,304 B of ws)

    hipLaunchKernelGGL(prep_kernel, dim3(48), dim3(256), 0, stream, Wp, W, wpf, wf);

    const int n_pos = 64 * 1024;
    hipLaunchKernelGGL(capsule_kernel, dim3(n_pos / TP), dim3(256), 0, stream,
                       X, bp, wpf, wf, out);
}

// Round 5
// 325.426 us; speedup vs baseline: 1.0897x; 1.0139x over previous
//
#include <hip/hip_runtime.h>
#include <hip/hip_bf16.h>
#include <math.h>

// B=64, L=1024, C=128, K=6, P=6, Dp=8, D=4, Dd=12, ITERS=2
// R3 lesson: VALU-issue was cut (56->35%) but time barely moved -> latency/barrier-bound.
// R5 change: (a) stage-1 X loads prefetched one chunk ahead (register pipeline, T14);
// (b) ALL barriers are raw s_barrier + lgkmcnt(0) only — __syncthreads() emits
// s_waitcnt vmcnt(0) which drains the prefetch and exposes full HBM latency 4x/block.
#define EPSQ 1e-9f

typedef float  floatx4 __attribute__((ext_vector_type(4)));
typedef short  short8  __attribute__((ext_vector_type(8)));
typedef unsigned short u16;
typedef unsigned int   u32;

constexpr int TP  = 16;  // positions per block
constexpr int SA  = 40;  // ushort stride, stage-1 A rows (32 data + 8 pad) = 80 B, 16B-aligned
constexpr int SS  = 49;  // dword stride, sU rows (48 data + 1 pad) = 196 B
constexpr int SA2 = 48;  // ushort stride, stage-2 A rows (48 data) = 96 B, 16B-aligned

// LDS plan (single overlaid region, phases separated by barriers):
//   phase 1: sA   = [96][SA] u16 hi + lo           = 15,360 B   (stage-1 X staging)
//   phase 2: sA2  = [96][SA2] u16 hi + lo          = 18,432 B   (stage-2 A fragments)
//   phase 3: sU   = [96][SS] f32                   = 18,816 B   (u_hat for routing)
//   + 32 B zero block at 18,816 for quad>=2 chunk-1 A-fragment reads
// total 18,848 B -> LDS admits 8 blocks/CU.
// R1 lesson: (256,8)'s 64-reg cap forced ~240 MB scratch spill. (256,6) = 85-reg cap.

// Raw barrier: LDS-visibility drain only (lgkmcnt), vmem stays in flight across it.
// Memory-clobber asm on both sides pins LDS ops to their phase (compiler fence).
#define BAR_LGKM() do {                                          \
    asm volatile("s_waitcnt lgkmcnt(0)" ::: "memory");           \
    __builtin_amdgcn_s_barrier();                                \
    asm volatile("" ::: "memory");                               \
} while (0)

// fast ~1-ulp hardware approximations (v_rcp_f32 / v_sqrt_f32)
__device__ __forceinline__ float fast_rcp(float x)  { return __builtin_amdgcn_rcpf(x); }
__device__ __forceinline__ float fast_sqrt(float x) { return __builtin_amdgcn_sqrtf(x); }

// squash scale factor: s2/(1+s2)/(sqrt(s2)+eps)
__device__ __forceinline__ float squash_rf(float s2) {
    return s2 * fast_rcp(1.0f + s2) * fast_rcp(fast_sqrt(s2) + EPSQ);
}

// fp32 -> (hi, lo) bf16 pair-packed as u32 (2 elements per call)
__device__ __forceinline__ void cvt_hilo(float a, float b, u32& hi, u32& lo) {
    __hip_bfloat162 h = __float22bfloat162_rn(make_float2(a, b));
    float2 hf = __bfloat1622float2(h);
    __hip_bfloat162 l = __float22bfloat162_rn(make_float2(a - hf.x, b - hf.y));
    __builtin_memcpy(&hi, &h, 4);
    __builtin_memcpy(&lo, &l, 4);
}

__device__ __forceinline__ float g16sum(float x) {
    x += __shfl_xor(x, 1);
    x += __shfl_xor(x, 2);
    x += __shfl_xor(x, 4);
    x += __shfl_xor(x, 8);
    return x;
}

__device__ __forceinline__ float g8sum(float x) {
    x += __shfl_xor(x, 1);
    x += __shfl_xor(x, 2);
    x += __shfl_xor(x, 4);
    return x;
}

// Dynamic routing (ITERS=2), named scalars only.
__device__ __forceinline__ void route_and_write(float u0, float u1, float u2,
                                                float u3, float u4, float u5,
                                                int d, int q, bool act,
                                                float* __restrict__ out, long pos)
{
    float s = (u0 + u1 + u2 + u3 + u4 + u5) * 0.25f;
    float s2 = g16sum(s * s);
    float v = s * squash_rf(s2);

    float ss = 0.f;
#define ROUTE_K(UK)                                        \
    {                                                      \
        float b = g16sum((UK) * v);                        \
        float mm = fmaxf(b, __shfl_xor(b, 16));            \
        mm = fmaxf(mm, __shfl_xor(mm, 32));                \
        float e = __expf(b - mm);                          \
        float es = e + __shfl_xor(e, 16);                  \
        es += __shfl_xor(es, 32);                          \
        ss = fmaf(e * fast_rcp(es), (UK), ss);             \
    }
    ROUTE_K(u0) ROUTE_K(u1) ROUTE_K(u2) ROUTE_K(u3) ROUTE_K(u4) ROUTE_K(u5)
#undef ROUTE_K
    float ss2 = g16sum(ss * ss);
    float vv = ss * squash_rf(ss2);
    if (act) out[pos * 48 + d * 12 + q] = vv;
}

// ---- prep: convert Wp/W into MFMA-B-fragment-ready bf16 hi/lo layouts in ws. (UNCHANGED)
// wpf: [var2][ct3][kc4][lane64][j8]  = Wp[p=ct*16+(lane&15)][c=kc*32+quad*8+j]
// wf : [var2][k6][ct3][kc2][lane64][j8] = W[k][dq=ct*16+(lane&15)][p=kc*32+quad*8+j], 0 if p>=48
__global__ void prep_kernel(const float* __restrict__ Wp, const float* __restrict__ W,
                            u16* __restrict__ wpf, u16* __restrict__ wf) {
    int gid = blockIdx.x * 256 + threadIdx.x;
    int stride = gridDim.x * 256;
    for (int i = gid; i < 12288; i += stride) {
        int j = i & 7, lane = (i >> 3) & 63, kc = (i >> 9) & 3, vt = i >> 11;
        int var = (vt >= 3) ? 1 : 0;
        int ct = vt - 3 * var;
        int p = ct * 16 + (lane & 15);
        int c = kc * 32 + (lane >> 4) * 8 + j;
        float x = Wp[p * 128 + c];
        __hip_bfloat16 hb = __float2bfloat16(x);
        if (var) { float hf = __bfloat162float(hb); hb = __float2bfloat16(x - hf); }
        u16 u; __builtin_memcpy(&u, &hb, 2);
        wpf[i] = u;
    }
    for (int i = gid; i < 36864; i += stride) {
        int j = i & 7, lane = (i >> 3) & 63, kc = (i >> 9) & 1, q3 = i >> 10;
        int ct = q3 % 3, kk = q3 / 3;       // kk = var*6 + k
        int k = kk % 6, var = kk / 6;
        int dq = ct * 16 + (lane & 15);
        int p = kc * 32 + (lane >> 4) * 8 + j;
        float x = (p < 48) ? W[(k * 48 + dq) * 48 + p] : 0.f;
        __hip_bfloat16 hb = __float2bfloat16(x);
        if (var) { float hf = __bfloat162float(hb); hb = __float2bfloat16(x - hf); }
        u16 u; __builtin_memcpy(&u, &hb, 2);
        wf[i] = u;
    }
}

__global__ __launch_bounds__(256, 6)
void capsule_kernel(
    const float* __restrict__ X,    // [65536][128][6]
    const float* __restrict__ bp,   // [48]
    const u16* __restrict__ wpf,    // prepped Wp fragments
    const u16* __restrict__ wf,     // prepped W fragments
    float* __restrict__ out)        // [65536][48]
{
    __shared__ __align__(16) char raw[18848];
    u16*   sAh  = (u16*)raw;                 // [96][SA]  (phase 1)
    u16*   sAl  = sAh + 96 * SA;
    u16*   sA2h = (u16*)raw;                 // [96][SA2] (phase 2, overlays sA)
    u16*   sA2l = sA2h + 96 * SA2;
    float* sU   = (float*)raw;               // [96][SS]  (phase 3, overlays sA2)
    const u16* zpad = (const u16*)(raw + 18816);  // 32 B of zeros

    const int t    = threadIdx.x;
    const int lane = t & 63;
    const int w    = t >> 6;
    const int m    = lane & 15;
    const int quad = lane >> 4;
    const long pos_base = (long)blockIdx.x * TP;

    if (t < 8) ((u32*)(raw + 18816))[t] = 0u;   // zero block (drained at first BAR_LGKM)

    // ================= stage 1: projection, 2-deep register-prefetch pipeline ==========
    // per kc: {cvt+ds_write chunk kc ; issue global loads chunk kc+1 ; lgkm-barrier ;
    //          MFMA on chunk kc ; lgkm-barrier}. X-load latency hides under MFMA+barrier.
    floatx4 acc_a = {0.f,0.f,0.f,0.f}, acc_b = {0.f,0.f,0.f,0.f}, acc_c = {0.f,0.f,0.f,0.f},
            acc_d = {0.f,0.f,0.f,0.f}, acc_e = {0.f,0.f,0.f,0.f};

    const int posS = t >> 4, cp = t & 15;
    const float4* xsrc = (const float4*)(X + (pos_base + posS) * 768) + cp * 3;  // +48/chunk
    u16* wbh = sAh + (posS * 6) * SA + cp * 2;
    u16* wbl = sAl + (posS * 6) * SA + cp * 2;

#define CVT_WRITE(F0, F1, F2)                                                                 \
    {   u32 h, l;                                                                             \
        cvt_hilo(F0.x, F1.z, h, l); *(u32*)(wbh + 0 * SA) = h; *(u32*)(wbl + 0 * SA) = l;     \
        cvt_hilo(F0.y, F1.w, h, l); *(u32*)(wbh + 1 * SA) = h; *(u32*)(wbl + 1 * SA) = l;     \
        cvt_hilo(F0.z, F2.x, h, l); *(u32*)(wbh + 2 * SA) = h; *(u32*)(wbl + 2 * SA) = l;     \
        cvt_hilo(F0.w, F2.y, h, l); *(u32*)(wbh + 3 * SA) = h; *(u32*)(wbl + 3 * SA) = l;     \
        cvt_hilo(F1.x, F2.z, h, l); *(u32*)(wbh + 4 * SA) = h; *(u32*)(wbl + 4 * SA) = l;     \
        cvt_hilo(F1.y, F2.w, h, l); *(u32*)(wbh + 5 * SA) = h; *(u32*)(wbl + 5 * SA) = l;     \
    }

#define S1_TILE(ACC, TI, KC)                                                          \
    { int T = w + 4 * (TI);                                                           \
      if (T < 18) {                                                                   \
        int rt = T / 3, ct = T - 3 * rt;                                              \
        short8 ah = *(const short8*)(sAh + (rt * 16 + m) * SA + quad * 8);            \
        short8 al = *(const short8*)(sAl + (rt * 16 + m) * SA + quad * 8);            \
        short8 bh = *(const short8*)(wpf + ((ct * 4 + (KC)) * 64 + lane) * 8);        \
        short8 bl = *(const short8*)(wpf + (((3 + ct) * 4 + (KC)) * 64 + lane) * 8);  \
        ACC = __builtin_amdgcn_mfma_f32_16x16x32_bf16(ah, bh, ACC, 0, 0, 0);          \
        ACC = __builtin_amdgcn_mfma_f32_16x16x32_bf16(ah, bl, ACC, 0, 0, 0);          \
        ACC = __builtin_amdgcn_mfma_f32_16x16x32_bf16(al, bh, ACC, 0, 0, 0);          \
      } }

#define S1_PHASE(KC)                                                         \
    S1_TILE(acc_a, 0, KC) S1_TILE(acc_b, 1, KC) S1_TILE(acc_c, 2, KC)        \
    S1_TILE(acc_d, 3, KC) S1_TILE(acc_e, 4, KC)

    float4 fa0 = xsrc[0],   fa1 = xsrc[1],   fa2 = xsrc[2];    // chunk 0
    float4 fb0 = xsrc[48],  fb1 = xsrc[49],  fb2 = xsrc[50];   // chunk 1 (in flight)
    CVT_WRITE(fa0, fa1, fa2);
    BAR_LGKM();
    S1_PHASE(0)
    BAR_LGKM();

    fa0 = xsrc[96];  fa1 = xsrc[97];  fa2 = xsrc[98];          // issue chunk 2
    CVT_WRITE(fb0, fb1, fb2);
    BAR_LGKM();
    S1_PHASE(1)
    BAR_LGKM();

    fb0 = xsrc[144]; fb1 = xsrc[145]; fb2 = xsrc[146];         // issue chunk 3
    CVT_WRITE(fa0, fa1, fa2);
    BAR_LGKM();
    S1_PHASE(2)
    BAR_LGKM();

    CVT_WRITE(fb0, fb1, fb2);
    BAR_LGKM();
    S1_PHASE(3)
    BAR_LGKM();   // also: all stage-1 reads of sA done before sA2 overlays it
#undef S1_PHASE
#undef S1_TILE
#undef CVT_WRITE

    // ===== fused epilogue: bias + squash (shfl over the 8-lane p-group) + bf16 hi/lo =====
    // C frag: value(row = rt*16+quad*4+r, col = ct*16+m); squash group = cols [g*8, g*8+8)
    // -> lanes differing in m&7 only -> g8sum. Write straight into stage-2 A layout.
#define FUSE_ONE(V)                                                   \
    { float val = (V) + bv;                                           \
      float s2 = g8sum(val * val);                                    \
      float sv = val * squash_rf(s2);                                 \
      __hip_bfloat16 hb = __float2bfloat16(sv);                       \
      float hf = __bfloat162float(hb);                                \
      __hip_bfloat16 lb = __float2bfloat16(sv - hf);                  \
      u16 hu, lu;                                                     \
      __builtin_memcpy(&hu, &hb, 2); __builtin_memcpy(&lu, &lb, 2);   \
      int dr = (kk * 16 + pp) * SA2 + ct * 16 + m;                    \
      sA2h[dr] = hu; sA2l[dr] = lu; }

#define S1_FUSE(ACC, TI)                                              \
    { int T = w + 4 * (TI);                                           \
      if (T < 18) {                                                   \
        int rt = T / 3, ct = T - 3 * rt;                              \
        float bv = bp[ct * 16 + m];                                   \
        int row0 = rt * 16 + quad * 4;                                \
        int pp = row0 / 6, kk = row0 - 6 * pp;                        \
        FUSE_ONE(ACC.x)                                               \
        kk++; if (kk == 6) { kk = 0; pp++; }                          \
        FUSE_ONE(ACC.y)                                               \
        kk++; if (kk == 6) { kk = 0; pp++; }                          \
        FUSE_ONE(ACC.z)                                               \
        kk++; if (kk == 6) { kk = 0; pp++; }                          \
        FUSE_ONE(ACC.w)                                               \
      } }
    S1_FUSE(acc_a, 0) S1_FUSE(acc_b, 1) S1_FUSE(acc_c, 2) S1_FUSE(acc_d, 3) S1_FUSE(acc_e, 4)
#undef S1_FUSE
#undef FUSE_ONE
    BAR_LGKM();   // sA2 visible to all waves

    // ================= stage 2: u_hat = Xp · W^T, both K-chunks back-to-back ==============
    // chunk 1 covers p=32..63: A cols 48..63 come from the zero block (broadcast, free);
    // B rows 48..63 are zeros from prep. Chunk 0 fully consumed before chunk 1 loads.
    floatx4 uacc_a = {0.f,0.f,0.f,0.f}, uacc_b = {0.f,0.f,0.f,0.f}, uacc_c = {0.f,0.f,0.f,0.f},
            uacc_d = {0.f,0.f,0.f,0.f}, uacc_e = {0.f,0.f,0.f,0.f};

#define S2_TILE(ACC, TI)                                                                      \
    { int T = w + 4 * (TI);                                                                   \
      if (T < 18) {                                                                           \
        int k = T / 3, ct = T - 3 * k;                                                        \
        const u16* arh = sA2h + (k * 16 + m) * SA2;                                           \
        const u16* arl = sA2l + (k * 16 + m) * SA2;                                           \
        {                                                                                     \
          short8 ah0 = *(const short8*)(arh + quad * 8);                                      \
          short8 al0 = *(const short8*)(arl + quad * 8);                                      \
          short8 bh0 = *(const short8*)(wf + (((k * 3 + ct) * 2 + 0) * 64 + lane) * 8);       \
          short8 bl0 = *(const short8*)(wf + ((((6 + k) * 3 + ct) * 2 + 0) * 64 + lane) * 8); \
          ACC = __builtin_amdgcn_mfma_f32_16x16x32_bf16(ah0, bh0, ACC, 0, 0, 0);              \
          ACC = __builtin_amdgcn_mfma_f32_16x16x32_bf16(ah0, bl0, ACC, 0, 0, 0);              \
          ACC = __builtin_amdgcn_mfma_f32_16x16x32_bf16(al0, bh0, ACC, 0, 0, 0);              \
        }                                                                                     \
        {                                                                                     \
          const u16* a1h = (quad < 2) ? (arh + 32 + quad * 8) : zpad;                         \
          const u16* a1l = (quad < 2) ? (arl + 32 + quad * 8) : zpad;                         \
          short8 ah1 = *(const short8*)a1h;                                                   \
          short8 al1 = *(const short8*)a1l;                                                   \
          short8 bh1 = *(const short8*)(wf + (((k * 3 + ct) * 2 + 1) * 64 + lane) * 8);       \
          short8 bl1 = *(const short8*)(wf + ((((6 + k) * 3 + ct) * 2 + 1) * 64 + lane) * 8); \
          ACC = __builtin_amdgcn_mfma_f32_16x16x32_bf16(ah1, bh1, ACC, 0, 0, 0);              \
          ACC = __builtin_amdgcn_mfma_f32_16x16x32_bf16(ah1, bl1, ACC, 0, 0, 0);              \
          ACC = __builtin_amdgcn_mfma_f32_16x16x32_bf16(al1, bh1, ACC, 0, 0, 0);              \
        }                                                                                     \
      } }
    S2_TILE(uacc_a, 0) S2_TILE(uacc_b, 1) S2_TILE(uacc_c, 2) S2_TILE(uacc_d, 3) S2_TILE(uacc_e, 4)
#undef S2_TILE
    BAR_LGKM();   // all stage-2 reads of sA2 done before sU overlays it

    // epilogue: C frag -> sU
#define S2_EPI(ACC, TI)                                                   \
    { int T = w + 4 * (TI);                                               \
      if (T < 18) {                                                       \
        int k = T / 3, ct = T - 3 * k;                                    \
        sU[((quad * 4 + 0) * 6 + k) * SS + ct * 16 + m] = ACC.x;          \
        sU[((quad * 4 + 1) * 6 + k) * SS + ct * 16 + m] = ACC.y;          \
        sU[((quad * 4 + 2) * 6 + k) * SS + ct * 16 + m] = ACC.z;          \
        sU[((quad * 4 + 3) * 6 + k) * SS + ct * 16 + m] = ACC.w;          \
      } }
    S2_EPI(uacc_a, 0) S2_EPI(uacc_b, 1) S2_EPI(uacc_c, 2) S2_EPI(uacc_d, 3) S2_EPI(uacc_e, 4)
#undef S2_EPI
    BAR_LGKM();

    // ================= routing: wave handles 4 positions =================
    const int d = lane >> 4;
    const int q = lane & 15;
    const bool act = (q < 12);
    const int dqi = d * 12 + (act ? q : 0);

    #pragma unroll
    for (int i = 0; i < 4; ++i) {
        int pos = w * 4 + i;
        const float* u = sU + (pos * 6) * SS + dqi;
        float a0 = u[0 * SS], a1 = u[1 * SS], a2 = u[2 * SS];
        float a3 = u[3 * SS], a4 = u[4 * SS], a5 = u[5 * SS];
        if (!act) { a0 = a1 = a2 = a3 = a4 = a5 = 0.f; }
        route_and_write(a0, a1, a2, a3, a4, a5, d, q, act, out, pos_base + pos);
    }
}

extern "C" void kernel_launch(void* const* d_in, const int* in_sizes, int n_in,
                              void* d_out, int out_size, void* d_ws, size_t ws_size,
                              hipStream_t stream) {
    const float* X  = (const float*)d_in[0];   // [64,1024,128,6]
    const float* Wp = (const float*)d_in[1];   // [48,128]
    const float* bp = (const float*)d_in[2];   // [48]
    const float* W  = (const float*)d_in[3];   // [6,4,12,48]
    float* out = (float*)d_out;                // [65536,48]

    u16* wpf = (u16*)d_ws;            // 12288 u16 = 24,576 B
    u16* wf  = wpf + 12288;           // 36864 u16 = 73,728 B  (total 98,304 B of ws)

    hipLaunchKernelGGL(prep_kernel, dim3(48), dim3(256), 0, stream, Wp, W, wpf, wf);

    const int n_pos = 64 * 1024;
    hipLaunchKernelGGL(capsule_kernel, dim3(n_pos / TP), dim3(256), 0, stream,
                       X, bp, wpf, wf, out);
}

// Round 6
// 307.637 us; speedup vs baseline: 1.1527x; 1.0578x over previous
//
#include <hip/hip_runtime.h>
#include <hip/hip_bf16.h>
#include <math.h>

// B=64, L=1024, C=128, K=6, P=6, Dp=8, D=4, Dd=12, ITERS=2
// R5 lesson: latency-bound; routing's per-position serial shuffle chains (~240
// ds_swizzle/wave, 4 sequential positions) are the dominant dead time.
// R6 change: transposed lane-parallel routing. lane=(pos_local,d,q-group): q-reductions
// become lane-local FMA + quad_perm DPP; softmax-d = xor4/xor8 only (4 ops/k/wave);
// 4 positions route in parallel; 6 k-chains independent (ILP). u held in 18 regs.
#define EPSQ 1e-9f

typedef float  floatx4 __attribute__((ext_vector_type(4)));
typedef short  short8  __attribute__((ext_vector_type(8)));
typedef unsigned short u16;
typedef unsigned int   u32;

constexpr int TP  = 16;  // positions per block
constexpr int SA  = 40;  // ushort stride, stage-1 A rows (32 data + 8 pad) = 80 B, 16B-aligned
constexpr int SS  = 49;  // dword stride, sU rows (48 data + 1 pad) = 196 B
constexpr int SA2 = 48;  // ushort stride, stage-2 A rows (48 data) = 96 B, 16B-aligned

// LDS plan (single overlaid region, phases separated by barriers):
//   phase 1: sA   = [96][SA] u16 hi + lo           = 15,360 B   (stage-1 X staging)
//   phase 2: sA2  = [96][SA2] u16 hi + lo          = 18,432 B   (stage-2 A fragments)
//   phase 3: sU   = [96][SS] f32                   = 18,816 B   (u_hat for routing)
//   + 32 B zero block at 18,816 for quad>=2 chunk-1 A-fragment reads
// total 18,848 B -> LDS admits 8 blocks/CU.
// R1 lesson: (256,8)'s 64-reg cap forced ~240 MB scratch spill. (256,6) = 85-reg cap.

// Raw barrier: LDS-visibility drain only (lgkmcnt), vmem stays in flight across it.
#define BAR_LGKM() do {                                          \
    asm volatile("s_waitcnt lgkmcnt(0)" ::: "memory");           \
    __builtin_amdgcn_s_barrier();                                \
    asm volatile("" ::: "memory");                               \
} while (0)

// fast ~1-ulp hardware approximations (v_rcp_f32 / v_sqrt_f32)
__device__ __forceinline__ float fast_rcp(float x)  { return __builtin_amdgcn_rcpf(x); }
__device__ __forceinline__ float fast_sqrt(float x) { return __builtin_amdgcn_sqrtf(x); }

// squash scale factor: s2/(1+s2)/(sqrt(s2)+eps)
__device__ __forceinline__ float squash_rf(float s2) {
    return s2 * fast_rcp(1.0f + s2) * fast_rcp(fast_sqrt(s2) + EPSQ);
}

// fp32 -> (hi, lo) bf16 pair-packed as u32 (2 elements per call)
__device__ __forceinline__ void cvt_hilo(float a, float b, u32& hi, u32& lo) {
    __hip_bfloat162 h = __float22bfloat162_rn(make_float2(a, b));
    float2 hf = __bfloat1622float2(h);
    __hip_bfloat162 l = __float22bfloat162_rn(make_float2(a - hf.x, b - hf.y));
    __builtin_memcpy(&hi, &h, 4);
    __builtin_memcpy(&lo, &l, 4);
}

__device__ __forceinline__ float g8sum(float x) {
    x += __shfl_xor(x, 1);
    x += __shfl_xor(x, 2);
    x += __shfl_xor(x, 4);
    return x;
}

// ---- prep: convert Wp/W into MFMA-B-fragment-ready bf16 hi/lo layouts in ws. (UNCHANGED)
// wpf: [var2][ct3][kc4][lane64][j8]  = Wp[p=ct*16+(lane&15)][c=kc*32+quad*8+j]
// wf : [var2][k6][ct3][kc2][lane64][j8] = W[k][dq=ct*16+(lane&15)][p=kc*32+quad*8+j], 0 if p>=48
__global__ void prep_kernel(const float* __restrict__ Wp, const float* __restrict__ W,
                            u16* __restrict__ wpf, u16* __restrict__ wf) {
    int gid = blockIdx.x * 256 + threadIdx.x;
    int stride = gridDim.x * 256;
    for (int i = gid; i < 12288; i += stride) {
        int j = i & 7, lane = (i >> 3) & 63, kc = (i >> 9) & 3, vt = i >> 11;
        int var = (vt >= 3) ? 1 : 0;
        int ct = vt - 3 * var;
        int p = ct * 16 + (lane & 15);
        int c = kc * 32 + (lane >> 4) * 8 + j;
        float x = Wp[p * 128 + c];
        __hip_bfloat16 hb = __float2bfloat16(x);
        if (var) { float hf = __bfloat162float(hb); hb = __float2bfloat16(x - hf); }
        u16 u; __builtin_memcpy(&u, &hb, 2);
        wpf[i] = u;
    }
    for (int i = gid; i < 36864; i += stride) {
        int j = i & 7, lane = (i >> 3) & 63, kc = (i >> 9) & 1, q3 = i >> 10;
        int ct = q3 % 3, kk = q3 / 3;       // kk = var*6 + k
        int k = kk % 6, var = kk / 6;
        int dq = ct * 16 + (lane & 15);
        int p = kc * 32 + (lane >> 4) * 8 + j;
        float x = (p < 48) ? W[(k * 48 + dq) * 48 + p] : 0.f;
        __hip_bfloat16 hb = __float2bfloat16(x);
        if (var) { float hf = __bfloat162float(hb); hb = __float2bfloat16(x - hf); }
        u16 u; __builtin_memcpy(&u, &hb, 2);
        wf[i] = u;
    }
}

__global__ __launch_bounds__(256, 6)
void capsule_kernel(
    const float* __restrict__ X,    // [65536][128][6]
    const float* __restrict__ bp,   // [48]
    const u16* __restrict__ wpf,    // prepped Wp fragments
    const u16* __restrict__ wf,     // prepped W fragments
    float* __restrict__ out)        // [65536][48]
{
    __shared__ __align__(16) char raw[18848];
    u16*   sAh  = (u16*)raw;                 // [96][SA]  (phase 1)
    u16*   sAl  = sAh + 96 * SA;
    u16*   sA2h = (u16*)raw;                 // [96][SA2] (phase 2, overlays sA)
    u16*   sA2l = sA2h + 96 * SA2;
    float* sU   = (float*)raw;               // [96][SS]  (phase 3, overlays sA2)
    const u16* zpad = (const u16*)(raw + 18816);  // 32 B of zeros

    const int t    = threadIdx.x;
    const int lane = t & 63;
    const int w    = t >> 6;
    const int m    = lane & 15;
    const int quad = lane >> 4;
    const long pos_base = (long)blockIdx.x * TP;

    if (t < 8) ((u32*)(raw + 18816))[t] = 0u;   // zero block (drained at first BAR_LGKM)

    // ================= stage 1: projection, 2-deep register-prefetch pipeline ==========
    floatx4 acc_a = {0.f,0.f,0.f,0.f}, acc_b = {0.f,0.f,0.f,0.f}, acc_c = {0.f,0.f,0.f,0.f},
            acc_d = {0.f,0.f,0.f,0.f}, acc_e = {0.f,0.f,0.f,0.f};

    const int posS = t >> 4, cp = t & 15;
    const float4* xsrc = (const float4*)(X + (pos_base + posS) * 768) + cp * 3;  // +48/chunk
    u16* wbh = sAh + (posS * 6) * SA + cp * 2;
    u16* wbl = sAl + (posS * 6) * SA + cp * 2;

#define CVT_WRITE(F0, F1, F2)                                                                 \
    {   u32 h, l;                                                                             \
        cvt_hilo(F0.x, F1.z, h, l); *(u32*)(wbh + 0 * SA) = h; *(u32*)(wbl + 0 * SA) = l;     \
        cvt_hilo(F0.y, F1.w, h, l); *(u32*)(wbh + 1 * SA) = h; *(u32*)(wbl + 1 * SA) = l;     \
        cvt_hilo(F0.z, F2.x, h, l); *(u32*)(wbh + 2 * SA) = h; *(u32*)(wbl + 2 * SA) = l;     \
        cvt_hilo(F0.w, F2.y, h, l); *(u32*)(wbh + 3 * SA) = h; *(u32*)(wbl + 3 * SA) = l;     \
        cvt_hilo(F1.x, F2.z, h, l); *(u32*)(wbh + 4 * SA) = h; *(u32*)(wbl + 4 * SA) = l;     \
        cvt_hilo(F1.y, F2.w, h, l); *(u32*)(wbh + 5 * SA) = h; *(u32*)(wbl + 5 * SA) = l;     \
    }

#define S1_TILE(ACC, TI, KC)                                                          \
    { int T = w + 4 * (TI);                                                           \
      if (T < 18) {                                                                   \
        int rt = T / 3, ct = T - 3 * rt;                                              \
        short8 ah = *(const short8*)(sAh + (rt * 16 + m) * SA + quad * 8);            \
        short8 al = *(const short8*)(sAl + (rt * 16 + m) * SA + quad * 8);            \
        short8 bh = *(const short8*)(wpf + ((ct * 4 + (KC)) * 64 + lane) * 8);        \
        short8 bl = *(const short8*)(wpf + (((3 + ct) * 4 + (KC)) * 64 + lane) * 8);  \
        ACC = __builtin_amdgcn_mfma_f32_16x16x32_bf16(ah, bh, ACC, 0, 0, 0);          \
        ACC = __builtin_amdgcn_mfma_f32_16x16x32_bf16(ah, bl, ACC, 0, 0, 0);          \
        ACC = __builtin_amdgcn_mfma_f32_16x16x32_bf16(al, bh, ACC, 0, 0, 0);          \
      } }

#define S1_PHASE(KC)                                                         \
    S1_TILE(acc_a, 0, KC) S1_TILE(acc_b, 1, KC) S1_TILE(acc_c, 2, KC)        \
    S1_TILE(acc_d, 3, KC) S1_TILE(acc_e, 4, KC)

    float4 fa0 = xsrc[0],   fa1 = xsrc[1],   fa2 = xsrc[2];    // chunk 0
    float4 fb0 = xsrc[48],  fb1 = xsrc[49],  fb2 = xsrc[50];   // chunk 1 (in flight)
    CVT_WRITE(fa0, fa1, fa2);
    BAR_LGKM();
    S1_PHASE(0)
    BAR_LGKM();

    fa0 = xsrc[96];  fa1 = xsrc[97];  fa2 = xsrc[98];          // issue chunk 2
    CVT_WRITE(fb0, fb1, fb2);
    BAR_LGKM();
    S1_PHASE(1)
    BAR_LGKM();

    fb0 = xsrc[144]; fb1 = xsrc[145]; fb2 = xsrc[146];         // issue chunk 3
    CVT_WRITE(fa0, fa1, fa2);
    BAR_LGKM();
    S1_PHASE(2)
    BAR_LGKM();

    CVT_WRITE(fb0, fb1, fb2);
    BAR_LGKM();
    S1_PHASE(3)
    BAR_LGKM();   // also: all stage-1 reads of sA done before sA2 overlays it
#undef S1_PHASE
#undef S1_TILE
#undef CVT_WRITE

    // ===== fused epilogue: bias + squash (shfl over the 8-lane p-group) + bf16 hi/lo =====
#define FUSE_ONE(V)                                                   \
    { float val = (V) + bv;                                           \
      float s2 = g8sum(val * val);                                    \
      float sv = val * squash_rf(s2);                                 \
      __hip_bfloat16 hb = __float2bfloat16(sv);                       \
      float hf = __bfloat162float(hb);                                \
      __hip_bfloat16 lb = __float2bfloat16(sv - hf);                  \
      u16 hu, lu;                                                     \
      __builtin_memcpy(&hu, &hb, 2); __builtin_memcpy(&lu, &lb, 2);   \
      int dr = (kk * 16 + pp) * SA2 + ct * 16 + m;                    \
      sA2h[dr] = hu; sA2l[dr] = lu; }

#define S1_FUSE(ACC, TI)                                              \
    { int T = w + 4 * (TI);                                           \
      if (T < 18) {                                                   \
        int rt = T / 3, ct = T - 3 * rt;                              \
        float bv = bp[ct * 16 + m];                                   \
        int row0 = rt * 16 + quad * 4;                                \
        int pp = row0 / 6, kk = row0 - 6 * pp;                        \
        FUSE_ONE(ACC.x)                                               \
        kk++; if (kk == 6) { kk = 0; pp++; }                          \
        FUSE_ONE(ACC.y)                                               \
        kk++; if (kk == 6) { kk = 0; pp++; }                          \
        FUSE_ONE(ACC.z)                                               \
        kk++; if (kk == 6) { kk = 0; pp++; }                          \
        FUSE_ONE(ACC.w)                                               \
      } }
    S1_FUSE(acc_a, 0) S1_FUSE(acc_b, 1) S1_FUSE(acc_c, 2) S1_FUSE(acc_d, 3) S1_FUSE(acc_e, 4)
#undef S1_FUSE
#undef FUSE_ONE
    BAR_LGKM();   // sA2 visible to all waves

    // ================= stage 2: u_hat = Xp · W^T, both K-chunks back-to-back ==============
    floatx4 uacc_a = {0.f,0.f,0.f,0.f}, uacc_b = {0.f,0.f,0.f,0.f}, uacc_c = {0.f,0.f,0.f,0.f},
            uacc_d = {0.f,0.f,0.f,0.f}, uacc_e = {0.f,0.f,0.f,0.f};

#define S2_TILE(ACC, TI)                                                                      \
    { int T = w + 4 * (TI);                                                                   \
      if (T < 18) {                                                                           \
        int k = T / 3, ct = T - 3 * k;                                                        \
        const u16* arh = sA2h + (k * 16 + m) * SA2;                                           \
        const u16* arl = sA2l + (k * 16 + m) * SA2;                                           \
        {                                                                                     \
          short8 ah0 = *(const short8*)(arh + quad * 8);                                      \
          short8 al0 = *(const short8*)(arl + quad * 8);                                      \
          short8 bh0 = *(const short8*)(wf + (((k * 3 + ct) * 2 + 0) * 64 + lane) * 8);       \
          short8 bl0 = *(const short8*)(wf + ((((6 + k) * 3 + ct) * 2 + 0) * 64 + lane) * 8); \
          ACC = __builtin_amdgcn_mfma_f32_16x16x32_bf16(ah0, bh0, ACC, 0, 0, 0);              \
          ACC = __builtin_amdgcn_mfma_f32_16x16x32_bf16(ah0, bl0, ACC, 0, 0, 0);              \
          ACC = __builtin_amdgcn_mfma_f32_16x16x32_bf16(al0, bh0, ACC, 0, 0, 0);              \
        }                                                                                     \
        {                                                                                     \
          const u16* a1h = (quad < 2) ? (arh + 32 + quad * 8) : zpad;                         \
          const u16* a1l = (quad < 2) ? (arl + 32 + quad * 8) : zpad;                         \
          short8 ah1 = *(const short8*)a1h;                                                   \
          short8 al1 = *(const short8*)a1l;                                                   \
          short8 bh1 = *(const short8*)(wf + (((k * 3 + ct) * 2 + 1) * 64 + lane) * 8);       \
          short8 bl1 = *(const short8*)(wf + ((((6 + k) * 3 + ct) * 2 + 1) * 64 + lane) * 8); \
          ACC = __builtin_amdgcn_mfma_f32_16x16x32_bf16(ah1, bh1, ACC, 0, 0, 0);              \
          ACC = __builtin_amdgcn_mfma_f32_16x16x32_bf16(ah1, bl1, ACC, 0, 0, 0);              \
          ACC = __builtin_amdgcn_mfma_f32_16x16x32_bf16(al1, bh1, ACC, 0, 0, 0);              \
        }                                                                                     \
      } }
    S2_TILE(uacc_a, 0) S2_TILE(uacc_b, 1) S2_TILE(uacc_c, 2) S2_TILE(uacc_d, 3) S2_TILE(uacc_e, 4)
#undef S2_TILE
    BAR_LGKM();   // all stage-2 reads of sA2 done before sU overlays it

    // epilogue: C frag -> sU
#define S2_EPI(ACC, TI)                                                   \
    { int T = w + 4 * (TI);                                               \
      if (T < 18) {                                                       \
        int k = T / 3, ct = T - 3 * k;                                    \
        sU[((quad * 4 + 0) * 6 + k) * SS + ct * 16 + m] = ACC.x;          \
        sU[((quad * 4 + 1) * 6 + k) * SS + ct * 16 + m] = ACC.y;          \
        sU[((quad * 4 + 2) * 6 + k) * SS + ct * 16 + m] = ACC.z;          \
        sU[((quad * 4 + 3) * 6 + k) * SS + ct * 16 + m] = ACC.w;          \
      } }
    S2_EPI(uacc_a, 0) S2_EPI(uacc_b, 1) S2_EPI(uacc_c, 2) S2_EPI(uacc_d, 3) S2_EPI(uacc_e, 4)
#undef S2_EPI
    BAR_LGKM();

    // ================= routing: transposed lane-parallel =================
    // lane = (pos_local<<4) | (d<<2) | qg ; each lane owns q = qg*3 + {0,1,2} of one (pos,d).
    // q-reductions: lane-local FMA + quad sum (xor1/xor2 = DPP). softmax over d: xor4/xor8.
    // 4 positions per wave in parallel; 6 independent k-chains give ILP. u in 18 regs.
    {
        const int pl = lane >> 4;           // position within this wave's group of 4
        const int dd = (lane >> 2) & 3;     // d
        const int qg = lane & 3;            // q-group (3 q's)
        const int posl = w * 4 + pl;
        const float* up = sU + (posl * 6) * SS + dd * 12 + qg * 3;

        float u00=up[0*SS+0], u01=up[0*SS+1], u02=up[0*SS+2];
        float u10=up[1*SS+0], u11=up[1*SS+1], u12=up[1*SS+2];
        float u20=up[2*SS+0], u21=up[2*SS+1], u22=up[2*SS+2];
        float u30=up[3*SS+0], u31=up[3*SS+1], u32=up[3*SS+2];
        float u40=up[4*SS+0], u41=up[4*SS+1], u42=up[4*SS+2];
        float u50=up[5*SS+0], u51=up[5*SS+1], u52=up[5*SS+2];

        // iter 0: c uniform = 1/4 -> s = 0.25 * sum_k u ; v1 = squash(s)
        float s0 = (u00+u10+u20+u30+u40+u50) * 0.25f;
        float s1 = (u01+u11+u21+u31+u41+u51) * 0.25f;
        float s2 = (u02+u12+u22+u32+u42+u52) * 0.25f;
        float t2 = s0*s0 + s1*s1 + s2*s2;
        t2 += __shfl_xor(t2, 1);
        t2 += __shfl_xor(t2, 2);
        float rf = squash_rf(t2);
        float v0 = s0*rf, v1 = s1*rf, v2 = s2*rf;

        // iter 1: per k (independent chains): b_k = sum_q u*v1 ; c = softmax_d(b_k) ;
        //          o += c*u_k. Then v2 = squash(o) -> output.
        float o0 = 0.f, o1 = 0.f, o2 = 0.f;
#define RK(UA, UB, UC)                                            \
        { float bk = UA*v0 + UB*v1 + UC*v2;                       \
          bk += __shfl_xor(bk, 1);                                \
          bk += __shfl_xor(bk, 2);                                \
          float mm = fmaxf(bk, __shfl_xor(bk, 4));                \
          mm = fmaxf(mm, __shfl_xor(mm, 8));                      \
          float e = __expf(bk - mm);                              \
          float es = e + __shfl_xor(e, 4);                        \
          es += __shfl_xor(es, 8);                                \
          float c = e * fast_rcp(es);                             \
          o0 = fmaf(c, UA, o0);                                   \
          o1 = fmaf(c, UB, o1);                                   \
          o2 = fmaf(c, UC, o2); }
        RK(u00, u01, u02) RK(u10, u11, u12) RK(u20, u21, u22)
        RK(u30, u31, u32) RK(u40, u41, u42) RK(u50, u51, u52)
#undef RK
        float w2 = o0*o0 + o1*o1 + o2*o2;
        w2 += __shfl_xor(w2, 1);
        w2 += __shfl_xor(w2, 2);
        float rf2 = squash_rf(w2);
        float* op = out + (pos_base + posl) * 48 + dd * 12 + qg * 3;
        op[0] = o0 * rf2;
        op[1] = o1 * rf2;
        op[2] = o2 * rf2;
    }
}

extern "C" void kernel_launch(void* const* d_in, const int* in_sizes, int n_in,
                              void* d_out, int out_size, void* d_ws, size_t ws_size,
                              hipStream_t stream) {
    const float* X  = (const float*)d_in[0];   // [64,1024,128,6]
    const float* Wp = (const float*)d_in[1];   // [48,128]
    const float* bp = (const float*)d_in[2];   // [48]
    const float* W  = (const float*)d_in[3];   // [6,4,12,48]
    float* out = (float*)d_out;                // [65536,48]

    u16* wpf = (u16*)d_ws;            // 12288 u16 = 24,576 B
    u16* wf  = wpf + 12288;           // 36864 u16 = 73,728 B  (total 98,304 B of ws)

    hipLaunchKernelGGL(prep_kernel, dim3(48), dim3(256), 0, stream, Wp, W, wpf, wf);

    const int n_pos = 64 * 1024;
    hipLaunchKernelGGL(capsule_kernel, dim3(n_pos / TP), dim3(256), 0, stream,
                       X, bp, wpf, wf, out);
}